// Round 19
// baseline (255.201 us; speedup 1.0000x reference)
//
#include <hip/hip_runtime.h>

// SAGEHeteroConv on MI355X (gfx950)
// out_item = x_item @ W_ui_tgt + scatter_mean(x_user[edge_ui]) @ W_ui_src
// out_user = x_user @ W_iu_tgt + scatter_mean(x_item[edge_iu]) @ W_iu_src
// Projection commutes with mean. CSR build = two-level LDS counting sort.
// agg_mfma: each GEMM block's waves aggregate their OWN 16 output rows
// (fp8 gather, f32 accum, 4-deep MLP) into an LDS tile, then feed the
// MFMA mean-half A-frags straight from LDS -- no meanb round-trip.
// ALIASING RULE (round-17 crash fix): agg_mfma reads csr/xf8 while writing
// d_out, so csr/xf8u/xf8i live in d_ws; only part[] (dead after p4) in d_out.

#define D_FEAT 128

static constexpr int kNUser = 100000;
static constexpr int kNItem = 50000;
static constexpr int kNTot  = kNItem + kNUser;     // 150000
static constexpr int kIB    = (kNItem + 255) / 256;  // 196 item buckets
static constexpr int kUB    = (kNUser + 255) / 256;  // 391 user buckets
static constexpr int NBUCK  = kIB + kUB;             // 587
static constexpr int CHUNK  = 6250;                  // edges per partition block
static constexpr int NCHUNK = 512;                   // 512*6250 = 3.2M = 2E
static constexpr int SEGCAP = 9216;                  // max edges per bucket (+11 sigma)

typedef short bf16x8 __attribute__((ext_vector_type(8)));
typedef float f32x4 __attribute__((ext_vector_type(4)));
typedef float f32x2 __attribute__((ext_vector_type(2)));

__device__ inline unsigned bf16rne(float f) {
  const unsigned u = __float_as_uint(f);
  return (u + 0x7fffu + ((u >> 16) & 1u)) >> 16;
}

__device__ inline int bucket_of(int t) {
  return (t < kNItem) ? (t >> 8) : (kIB + ((t - kNItem) >> 8));
}

// ---------------------------------------------------------------------------
// phase_a: block-range fused {conv2 (blocks 0..2047) | pack_w (2048..2079) |
// p1 bucket hist (2080..2591)} -- three independent jobs share one dispatch.
// ---------------------------------------------------------------------------
__global__ __launch_bounds__(256) void phase_a_kernel(
    const float* __restrict__ xu, const float* __restrict__ xi,
    unsigned short* __restrict__ xbu, unsigned short* __restrict__ xbi,
    unsigned char* __restrict__ xf8u, unsigned char* __restrict__ xf8i,
    const float* __restrict__ Wt0, const float* __restrict__ Ws0,
    const float* __restrict__ Wt1, const float* __restrict__ Ws1,
    unsigned short* __restrict__ bp,
    const int* __restrict__ eui_t, const int* __restrict__ eiu_t,
    unsigned* __restrict__ gh, int n8u, int n8t, int E) {
  __shared__ unsigned lh[NBUCK];
  const int b = (int)blockIdx.x;
  const int tid = (int)threadIdx.x;

  if (b < 2048) {
    // ---- conv: f32 -> {bf16, fp8} both matrices ----
    for (int i = b * 256 + tid; i < n8t; i += 2048 * 256) {
      const float* in = (i < n8u) ? xu : xi;
      unsigned short* outb = (i < n8u) ? xbu : xbi;
      unsigned char* out8 = (i < n8u) ? xf8u : xf8i;
      const int j = (i < n8u) ? i : (i - n8u);
      const float4 a = ((const float4*)in)[(size_t)j * 2];
      const float4 c = ((const float4*)in)[(size_t)j * 2 + 1];
      uint4 r;
      r.x = bf16rne(a.x) | (bf16rne(a.y) << 16);
      r.y = bf16rne(a.z) | (bf16rne(a.w) << 16);
      r.z = bf16rne(c.x) | (bf16rne(c.y) << 16);
      r.w = bf16rne(c.z) | (bf16rne(c.w) << 16);
      ((uint4*)outb)[j] = r;
      uint2 q;
      q.x = (unsigned)__builtin_amdgcn_cvt_pk_fp8_f32(a.x, a.y, 0, false);
      q.x = (unsigned)__builtin_amdgcn_cvt_pk_fp8_f32(a.z, a.w, (int)q.x, true);
      q.y = (unsigned)__builtin_amdgcn_cvt_pk_fp8_f32(c.x, c.y, 0, false);
      q.y = (unsigned)__builtin_amdgcn_cvt_pk_fp8_f32(c.z, c.w, (int)q.y, true);
      ((uint2*)out8)[j] = q;
    }
  } else if (b < 2080) {
    // ---- pack_w: [W_tgt;W_src] x2 (256x128 f32) -> MFMA B-fragment bf16 ----
    const int t = (b - 2048) * 256 + tid;   // 0..8191
    if (t < 2 * 8 * 8 * 64) {
      const int pair = t >> 12;
      const int kk = (t >> 9) & 7;
      const int n = (t >> 6) & 7;
      const int l = t & 63;
      const int c = n * 16 + (l & 15);
      const int k0 = kk * 32 + (l >> 4) * 8;
      const float* Wt = pair ? Wt1 : Wt0;
      const float* Ws = pair ? Ws1 : Ws0;
      unsigned v[8];
#pragma unroll
      for (int j = 0; j < 8; ++j) {
        const int k = k0 + j;
        const float f = (k < 128) ? Wt[k * 128 + c] : Ws[(k - 128) * 128 + c];
        v[j] = bf16rne(f);
      }
      uint4 r;
      r.x = v[0] | (v[1] << 16);
      r.y = v[2] | (v[3] << 16);
      r.z = v[4] | (v[5] << 16);
      r.w = v[6] | (v[7] << 16);
      ((uint4*)bp)[t] = r;
    }
  } else {
    // ---- p1: bucket histogram (LDS hist, 1 global atomic per bucket) ----
    for (int k = tid; k < NBUCK; k += 256) lh[k] = 0;
    __syncthreads();
    const int total = 2 * E;
    const int beg = (b - 2080) * CHUNK;
    const int end = min(beg + CHUNK, total);
    for (int i = beg + tid; i < end; i += 256) {
      const int t = (i < E) ? eui_t[i] : (eiu_t[i - E] + kNItem);
      atomicAdd(&lh[bucket_of(t)], 1u);
    }
    __syncthreads();
    for (int k = tid; k < NBUCK; k += 256)
      if (lh[k]) atomicAdd(&gh[k], lh[k]);
  }
}

// ---------------------------------------------------------------------------
// P2: exclusive scan of gh[NBUCK] -> bstart[NBUCK+1]; init gcur = bstart
// ---------------------------------------------------------------------------
__global__ __launch_bounds__(256) void p2_scan_kernel(
    const unsigned* __restrict__ gh, unsigned* __restrict__ bstart,
    unsigned* __restrict__ gcur) {
  __shared__ unsigned ts[256];
  const int tid = threadIdx.x;
  unsigned v[4];
  unsigned tsum = 0;
#pragma unroll
  for (int i = 0; i < 4; ++i) {
    const int idx = tid * 4 + i;
    v[i] = (idx < NBUCK) ? gh[idx] : 0u;
    tsum += v[i];
  }
  ts[tid] = tsum;
  __syncthreads();
  unsigned x = tsum;
  for (int off = 1; off < 256; off <<= 1) {
    const unsigned y = (tid >= off) ? ts[tid - off] : 0u;
    __syncthreads();
    x += y;
    ts[tid] = x;
    __syncthreads();
  }
  unsigned run = x - tsum;
#pragma unroll
  for (int i = 0; i < 4; ++i) {
    const int idx = tid * 4 + i;
    if (idx < NBUCK) { bstart[idx] = run; gcur[idx] = run; }
    run += v[i];
  }
  if (tid == 255) bstart[NBUCK] = run;   // total
}

// ---------------------------------------------------------------------------
// P3: partition edges into bucket-contiguous part[] via LDS staging.
// Entry packed u32: src | (tl << 24). Bucket id recorded in u16 side array
// at scatter time -> flush does a direct lookup (no binary search).
// ---------------------------------------------------------------------------
__global__ __launch_bounds__(256) void p3_partition_kernel(
    const int* __restrict__ eui_s, const int* __restrict__ eui_t,
    const int* __restrict__ eiu_s, const int* __restrict__ eiu_t,
    unsigned* __restrict__ gcur, unsigned* __restrict__ part, int E) {
  __shared__ unsigned lh[NBUCK], lbase[NBUCK], lcur[NBUCK], lpref[NBUCK];
  __shared__ unsigned ts[256];
  __shared__ unsigned lstage[CHUNK];
  __shared__ unsigned short lbuck[CHUNK];
  const int tid = (int)threadIdx.x;
  for (int k = tid; k < NBUCK; k += 256) { lh[k] = 0; lcur[k] = 0; }
  __syncthreads();

  const int total = 2 * E;
  const int beg = (int)blockIdx.x * CHUNK;
  const int end = min(beg + CHUNK, total);
  const int csz = end - beg;

  // pass A: local bucket histogram
  for (int i = beg + tid; i < end; i += 256) {
    const int t = (i < E) ? eui_t[i] : (eiu_t[i - E] + kNItem);
    atomicAdd(&lh[bucket_of(t)], 1u);
  }
  __syncthreads();

  // reserve global ranges + local exclusive scan (lpref)
  for (int k = tid; k < NBUCK; k += 256)
    lbase[k] = lh[k] ? atomicAdd(&gcur[k], lh[k]) : 0u;
  {
    unsigned v[3];
    unsigned tsum = 0;
#pragma unroll
    for (int i = 0; i < 3; ++i) {            // 3*256 = 768 >= NBUCK
      const int idx = tid * 3 + i;
      v[i] = (idx < NBUCK) ? lh[idx] : 0u;
      tsum += v[i];
    }
    ts[tid] = tsum;
    __syncthreads();
    unsigned x = tsum;
    for (int off = 1; off < 256; off <<= 1) {
      const unsigned y = (tid >= off) ? ts[tid - off] : 0u;
      __syncthreads();
      x += y;
      ts[tid] = x;
      __syncthreads();
    }
    unsigned run = x - tsum;
#pragma unroll
    for (int i = 0; i < 3; ++i) {
      const int idx = tid * 3 + i;
      if (idx < NBUCK) lpref[idx] = run;
      run += v[i];
    }
  }
  __syncthreads();

  // pass B: scatter into bucket-sorted LDS staging (+ bucket id)
  for (int i = beg + tid; i < end; i += 256) {
    int s, t;
    if (i < E) { s = eui_s[i]; t = eui_t[i]; }
    else       { s = eiu_s[i - E]; t = eiu_t[i - E] + kNItem; }
    const int k = bucket_of(t);
    const unsigned tl = (t < kNItem) ? (unsigned)(t & 255) : (unsigned)((t - kNItem) & 255);
    const unsigned r = atomicAdd(&lcur[k], 1u);
    const unsigned idx = lpref[k] + r;
    lstage[idx] = (unsigned)s | (tl << 24);
    lbuck[idx] = (unsigned short)k;
  }
  __syncthreads();

  // flush: direct bucket lookup, bucket-contiguous runs to part[]
  for (int j = tid; j < csz; j += 256) {
    const int k = lbuck[j];
    part[lbase[k] + (j - lpref[k])] = lstage[j];
  }
}

// ---------------------------------------------------------------------------
// P4: per-bucket CSR (LDS hist + scan + staged segment -> coalesced writes)
// ---------------------------------------------------------------------------
__global__ __launch_bounds__(256) void p4_csr_kernel(
    const unsigned* __restrict__ part, const unsigned* __restrict__ bstart,
    unsigned* __restrict__ csr, unsigned* __restrict__ offs,
    unsigned* __restrict__ cnt) {
  __shared__ unsigned lcnt[256], lofs[256], lcur[256], ts[256];
  __shared__ unsigned segbuf[SEGCAP];
  const int k = (int)blockIdx.x;
  const int tid = (int)threadIdx.x;
  const unsigned seg0 = bstart[k], seg1 = bstart[k + 1];
  const int tbase = (k < kIB) ? (k << 8) : (kNItem + ((k - kIB) << 8));
  const int tmax = (k < kIB) ? min(256, kNItem - tbase) : min(256, kNTot - tbase);

  lcnt[tid] = 0;
  __syncthreads();
  for (unsigned i = seg0 + tid; i < seg1; i += 256)
    atomicAdd(&lcnt[part[i] >> 24], 1u);
  __syncthreads();

  const unsigned v = lcnt[tid];
  ts[tid] = v;
  __syncthreads();
  unsigned x = v;
  for (int off = 1; off < 256; off <<= 1) {
    const unsigned y = (tid >= off) ? ts[tid - off] : 0u;
    __syncthreads();
    x += y;
    ts[tid] = x;
    __syncthreads();
  }
  lofs[tid] = x - v;
  lcur[tid] = 0;
  if (tid < tmax) { offs[tbase + tid] = seg0 + (x - v); cnt[tbase + tid] = v; }
  __syncthreads();

  for (unsigned i = seg0 + tid; i < seg1; i += 256) {
    const unsigned e = part[i];
    const unsigned tl = e >> 24;
    const unsigned r = atomicAdd(&lcur[tl], 1u);
    const unsigned slot = lofs[tl] + r;
    if (slot < SEGCAP) segbuf[slot] = e & 0x00FFFFFFu;
  }
  __syncthreads();

  const unsigned segsz = min(seg1 - seg0, (unsigned)SEGCAP);
  for (unsigned j = tid; j < segsz; j += 256) csr[seg0 + j] = segbuf[j];
}

// ---------------------------------------------------------------------------
// agg_mfma: fused {per-wave fp8 gather-mean into LDS} + {bf16 MFMA GEMM}.
// Block owns 64 output rows; wave w aggregates rows w*16..w*16+15 (one node
// at a time, 16 lanes/row x 8B, 4 outstanding loads), packs bf16 means into
// mlds[64][136] (272B stride: 16B-aligned rows, 2-way-max banks). Then the
// GEMM reads x-half A-frags from global bf16 and mean-half from LDS.
// No __syncthreads: each wave reads only the LDS rows it wrote.
// C/D: col = lane&15, row = (lane>>4)*4 + reg   [verified m89 layout]
// ---------------------------------------------------------------------------
__global__ __launch_bounds__(256) void agg_mfma_kernel(
    const unsigned char* __restrict__ xf8u, const unsigned char* __restrict__ xf8i,
    const unsigned short* __restrict__ xbi, const unsigned short* __restrict__ xbu,
    const unsigned* __restrict__ csr, const unsigned* __restrict__ offs,
    const unsigned* __restrict__ cnt, const unsigned short* __restrict__ bpack,
    float* __restrict__ out_user, float* __restrict__ out_item, int itemBlocks) {
  __shared__ unsigned short mlds[64][136];   // 272B row stride

  const int b = (int)blockIdx.x;
  const unsigned char* xf;
  const unsigned short *xb, *bp;
  float* out;
  int M, rowb_blk, cidOff;
  if (b < itemBlocks) {
    M = kNItem; rowb_blk = b * 64; cidOff = 0;
    xf = xf8u; xb = xbi; out = out_item; bp = bpack;
  } else {
    M = kNUser; rowb_blk = (b - itemBlocks) * 64; cidOff = kNItem;
    xf = xf8i; xb = xbu; out = out_user;
    bp = bpack + (size_t)8 * 8 * 64 * 8;
  }

  const int l = (int)(threadIdx.x & 63);
  const int w = (int)(threadIdx.x >> 6);
  const int sub = l >> 4;
  const unsigned sl8 = (unsigned)(l & 15) * 8u;

  // ---- phase 1: aggregate this wave's 16 rows into LDS ----
#pragma unroll 1
  for (int i = 0; i < 16; ++i) {
    const int r = w * 16 + i;
    const int nl = min(rowb_blk + r, M - 1);
    const int cid = cidOff + nl;
    const unsigned deg = cnt[cid];
    const unsigned start = offs[cid];
    const unsigned end = start + deg;

    f32x2 a0 = {0.f, 0.f}, a1 = {0.f, 0.f}, a2 = {0.f, 0.f}, a3 = {0.f, 0.f};
    unsigned base = start;
    for (; base + 16 <= end; base += 16) {
      const unsigned s0 = csr[base + sub];
      const unsigned s1 = csr[base + sub + 4];
      const unsigned s2 = csr[base + sub + 8];
      const unsigned s3 = csr[base + sub + 12];
      const uint2 v0 = *(const uint2*)(xf + (size_t)(s0 * 128u + sl8));
      const uint2 v1 = *(const uint2*)(xf + (size_t)(s1 * 128u + sl8));
      const uint2 v2 = *(const uint2*)(xf + (size_t)(s2 * 128u + sl8));
      const uint2 v3 = *(const uint2*)(xf + (size_t)(s3 * 128u + sl8));
#pragma unroll
      for (int h = 0; h < 4; ++h) {
        const uint2 v = (h == 0) ? v0 : (h == 1) ? v1 : (h == 2) ? v2 : v3;
        a0 += __builtin_amdgcn_cvt_pk_f32_fp8((int)v.x, false);
        a1 += __builtin_amdgcn_cvt_pk_f32_fp8((int)v.x, true);
        a2 += __builtin_amdgcn_cvt_pk_f32_fp8((int)v.y, false);
        a3 += __builtin_amdgcn_cvt_pk_f32_fp8((int)v.y, true);
      }
    }
    if (base < end) {                       // single guarded 4-deep tail
      const unsigned i0 = base + sub;
      const unsigned i1 = i0 + 4;
      const unsigned i2 = i0 + 8;
      const unsigned i3 = i0 + 12;
      uint2 v0 = make_uint2(0, 0), v1 = make_uint2(0, 0);
      uint2 v2 = make_uint2(0, 0), v3 = make_uint2(0, 0);
      if (i0 < end) v0 = *(const uint2*)(xf + (size_t)(csr[i0] * 128u + sl8));
      if (i1 < end) v1 = *(const uint2*)(xf + (size_t)(csr[i1] * 128u + sl8));
      if (i2 < end) v2 = *(const uint2*)(xf + (size_t)(csr[i2] * 128u + sl8));
      if (i3 < end) v3 = *(const uint2*)(xf + (size_t)(csr[i3] * 128u + sl8));
#pragma unroll
      for (int h = 0; h < 4; ++h) {
        const uint2 v = (h == 0) ? v0 : (h == 1) ? v1 : (h == 2) ? v2 : v3;
        a0 += __builtin_amdgcn_cvt_pk_f32_fp8((int)v.x, false);
        a1 += __builtin_amdgcn_cvt_pk_f32_fp8((int)v.x, true);
        a2 += __builtin_amdgcn_cvt_pk_f32_fp8((int)v.y, false);
        a3 += __builtin_amdgcn_cvt_pk_f32_fp8((int)v.y, true);
      }
    }

    float acc[8] = {a0.x, a0.y, a1.x, a1.y, a2.x, a2.y, a3.x, a3.y};
#pragma unroll
    for (int j = 0; j < 8; ++j) acc[j] += __shfl_xor(acc[j], 16);
#pragma unroll
    for (int j = 0; j < 8; ++j) acc[j] += __shfl_xor(acc[j], 32);

    if (sub == 0) {
      const float inv = deg ? 1.0f / (float)deg : 0.0f;  // zero rows stay zero
      uint4 rr;
      rr.x = bf16rne(acc[0] * inv) | (bf16rne(acc[1] * inv) << 16);
      rr.y = bf16rne(acc[2] * inv) | (bf16rne(acc[3] * inv) << 16);
      rr.z = bf16rne(acc[4] * inv) | (bf16rne(acc[5] * inv) << 16);
      rr.w = bf16rne(acc[6] * inv) | (bf16rne(acc[7] * inv) << 16);
      *(uint4*)&mlds[r][(l & 15) * 8] = rr;
    }
  }
  // wave-private LDS rows -> no barrier needed (compiler orders ds ops via lgkmcnt)

  // ---- phase 2: GEMM (x-half from global bf16, mean-half from LDS) ----
  const int rowb = rowb_blk + w * 16;
  const int arow = min(rowb + (l & 15), M - 1);
  const int kq8 = (l >> 4) * 8;

  f32x4 acc[8];
#pragma unroll
  for (int n = 0; n < 8; ++n) acc[n] = (f32x4){0.f, 0.f, 0.f, 0.f};

  const unsigned short* ax = xb + (size_t)arow * D_FEAT + kq8;

#pragma unroll
  for (int kk = 0; kk < 4; ++kk) {
    const bf16x8 a = *(const bf16x8*)(ax + kk * 32);
#pragma unroll
    for (int n = 0; n < 8; ++n) {
      const bf16x8 bfr = *(const bf16x8*)(bp + ((size_t)(kk * 8 + n) * 64 + l) * 8);
      acc[n] = __builtin_amdgcn_mfma_f32_16x16x32_bf16(a, bfr, acc[n], 0, 0, 0);
    }
  }
  const unsigned short* aml = &mlds[w * 16 + (l & 15)][kq8];
#pragma unroll
  for (int kk = 4; kk < 8; ++kk) {
    const bf16x8 a = *(const bf16x8*)(aml + (kk - 4) * 32);
#pragma unroll
    for (int n = 0; n < 8; ++n) {
      const bf16x8 bfr = *(const bf16x8*)(bp + ((size_t)(kk * 8 + n) * 64 + l) * 8);
      acc[n] = __builtin_amdgcn_mfma_f32_16x16x32_bf16(a, bfr, acc[n], 0, 0, 0);
    }
  }

  const int r0 = rowb + (l >> 4) * 4;
  const int col = l & 15;
#pragma unroll
  for (int n = 0; n < 8; ++n) {
#pragma unroll
    for (int r = 0; r < 4; ++r) {
      const int row = r0 + r;
      if (row < M) out[(size_t)row * 128 + n * 16 + col] = acc[n][r];
    }
  }
}

// ---------------------------------------------------------------------------
extern "C" void kernel_launch(void* const* d_in, const int* in_sizes, int n_in,
                              void* d_out, int out_size, void* d_ws, size_t ws_size,
                              hipStream_t stream) {
  const float* x_user  = (const float*)d_in[0];
  const float* x_item  = (const float*)d_in[1];
  const float* W_ui_src = (const float*)d_in[2];
  const float* W_ui_tgt = (const float*)d_in[3];
  const float* W_iu_src = (const float*)d_in[4];
  const float* W_iu_tgt = (const float*)d_in[5];
  const int* edge_ui = (const int*)d_in[6];
  const int* edge_iu = (const int*)d_in[7];
  const int E = in_sizes[6] / 2;   // 1,600,000

  // ws (~71.7 MB): xbu[100K*128]bf16, xbi[50K*128]bf16, bpack[2*256*128]bf16,
  //   gh[587], bstart[588], gcur[587], cnt[150K], offs[150K],
  //   csr[2E] u32, xf8u[100K*128] u8, xf8i[50K*128] u8
  //   (csr/xf8 MUST be in ws: agg_mfma reads them while writing d_out)
  unsigned short* xbu   = (unsigned short*)d_ws;
  unsigned short* xbi   = xbu + (size_t)kNUser * 128;
  unsigned short* bpack = xbi + (size_t)kNItem * 128;
  unsigned* gh     = (unsigned*)(bpack + 2 * 256 * 128);
  unsigned* bstart = gh + NBUCK;
  unsigned* gcur   = bstart + (NBUCK + 1);
  unsigned* cnt    = gcur + NBUCK;
  unsigned* offs   = cnt + kNTot;
  unsigned* csr    = offs + kNTot;
  unsigned char* xf8u = (unsigned char*)(csr + (size_t)2 * E);
  unsigned char* xf8i = xf8u + (size_t)kNUser * 128;

  float* out_user = (float*)d_out;                 // return order: user first
  float* out_item = out_user + (size_t)kNUser * 128;

  // d_out scratch: part[2E] u32 (12.8 MB) -- fully consumed by p4_csr BEFORE
  // agg_mfma writes d_out (same-stream ordering), never read afterward.
  unsigned* part = (unsigned*)d_out;

  hipMemsetAsync(gh, 0, NBUCK * sizeof(unsigned), stream);

  // fused convert | pack | histogram (2048 + 32 + 512 blocks)
  phase_a_kernel<<<2048 + 32 + NCHUNK, 256, 0, stream>>>(
      x_user, x_item, xbu, xbi, xf8u, xf8i,
      W_ui_tgt, W_ui_src, W_iu_tgt, W_iu_src, bpack,
      edge_ui + E, edge_iu + E, gh,
      kNUser * 128 / 8, kNTot * 128 / 8, E);

  p2_scan_kernel<<<1, 256, 0, stream>>>(gh, bstart, gcur);
  p3_partition_kernel<<<NCHUNK, 256, 0, stream>>>(
      edge_ui, edge_ui + E, edge_iu, edge_iu + E, gcur, part, E);
  p4_csr_kernel<<<NBUCK, 256, 0, stream>>>(part, bstart, csr, offs, cnt);

  const int itemBlocks = (kNItem + 63) / 64;       // 782
  const int userBlocks = (kNUser + 63) / 64;       // 1563
  agg_mfma_kernel<<<itemBlocks + userBlocks, 256, 0, stream>>>(
      xf8u, xf8i, xbi, xbu, csr, offs, cnt, bpack,
      out_user, out_item, itemBlocks);
}

// Round 21
// 204.044 us; speedup vs baseline: 1.2507x; 1.2507x over previous
//
#include <hip/hip_runtime.h>

// SAGEHeteroConv on MI355X (gfx950)
// out_item = x_item @ W_ui_tgt + scatter_mean(x_user[edge_ui]) @ W_ui_src
// out_user = x_user @ W_iu_tgt + scatter_mean(x_item[edge_iu]) @ W_iu_src
// Projection commutes with mean. Aggregate gathers FP8(e4m3) rows (f32 accum,
// quant noise averaged by the mean), writes bf16 means; fused bf16 MFMA GEMM.
// CSR build = two-level LDS counting sort (LDS atomics only, no binary search).
// phase_a = fused {f32->bf16/fp8 convert | weight pack | bucket histogram}.
// Aggregate: 16 lanes/row x 8B loads, 4 outstanding/lane, v_pk_add_f32 accum.
// NOTE (round-18 lesson): do NOT fuse aggregate into the GEMM -- the gather is
// latency-bound and needs the split kernel's full occupancy (fused = 35% occ,
// +50 us). The meanb round-trip (~12 us of BW) is the cheaper trade.

#define D_FEAT 128

static constexpr int kNUser = 100000;
static constexpr int kNItem = 50000;
static constexpr int kNTot  = kNItem + kNUser;     // 150000
static constexpr int kIB    = (kNItem + 255) / 256;  // 196 item buckets
static constexpr int kUB    = (kNUser + 255) / 256;  // 391 user buckets
static constexpr int NBUCK  = kIB + kUB;             // 587
static constexpr int CHUNK  = 6250;                  // edges per partition block
static constexpr int NCHUNK = 512;                   // 512*6250 = 3.2M = 2E
static constexpr int SEGCAP = 9216;                  // max edges per bucket (+11 sigma)

typedef short bf16x8 __attribute__((ext_vector_type(8)));
typedef float f32x4 __attribute__((ext_vector_type(4)));
typedef float f32x2 __attribute__((ext_vector_type(2)));

__device__ inline unsigned bf16rne(float f) {
  const unsigned u = __float_as_uint(f);
  return (u + 0x7fffu + ((u >> 16) & 1u)) >> 16;
}

__device__ inline int bucket_of(int t) {
  return (t < kNItem) ? (t >> 8) : (kIB + ((t - kNItem) >> 8));
}

// ---------------------------------------------------------------------------
// phase_a: block-range fused {conv2 (blocks 0..2047) | pack_w (2048..2079) |
// p1 bucket hist (2080..2591)} -- three independent jobs share one dispatch.
// ---------------------------------------------------------------------------
__global__ __launch_bounds__(256) void phase_a_kernel(
    const float* __restrict__ xu, const float* __restrict__ xi,
    unsigned short* __restrict__ xbu, unsigned short* __restrict__ xbi,
    unsigned char* __restrict__ xf8u, unsigned char* __restrict__ xf8i,
    const float* __restrict__ Wt0, const float* __restrict__ Ws0,
    const float* __restrict__ Wt1, const float* __restrict__ Ws1,
    unsigned short* __restrict__ bp,
    const int* __restrict__ eui_t, const int* __restrict__ eiu_t,
    unsigned* __restrict__ gh, int n8u, int n8t, int E) {
  __shared__ unsigned lh[NBUCK];
  const int b = (int)blockIdx.x;
  const int tid = (int)threadIdx.x;

  if (b < 2048) {
    // ---- conv: f32 -> {bf16, fp8} both matrices ----
    for (int i = b * 256 + tid; i < n8t; i += 2048 * 256) {
      const float* in = (i < n8u) ? xu : xi;
      unsigned short* outb = (i < n8u) ? xbu : xbi;
      unsigned char* out8 = (i < n8u) ? xf8u : xf8i;
      const int j = (i < n8u) ? i : (i - n8u);
      const float4 a = ((const float4*)in)[(size_t)j * 2];
      const float4 c = ((const float4*)in)[(size_t)j * 2 + 1];
      uint4 r;
      r.x = bf16rne(a.x) | (bf16rne(a.y) << 16);
      r.y = bf16rne(a.z) | (bf16rne(a.w) << 16);
      r.z = bf16rne(c.x) | (bf16rne(c.y) << 16);
      r.w = bf16rne(c.z) | (bf16rne(c.w) << 16);
      ((uint4*)outb)[j] = r;
      uint2 q;
      q.x = (unsigned)__builtin_amdgcn_cvt_pk_fp8_f32(a.x, a.y, 0, false);
      q.x = (unsigned)__builtin_amdgcn_cvt_pk_fp8_f32(a.z, a.w, (int)q.x, true);
      q.y = (unsigned)__builtin_amdgcn_cvt_pk_fp8_f32(c.x, c.y, 0, false);
      q.y = (unsigned)__builtin_amdgcn_cvt_pk_fp8_f32(c.z, c.w, (int)q.y, true);
      ((uint2*)out8)[j] = q;
    }
  } else if (b < 2080) {
    // ---- pack_w: [W_tgt;W_src] x2 (256x128 f32) -> MFMA B-fragment bf16 ----
    const int t = (b - 2048) * 256 + tid;   // 0..8191
    if (t < 2 * 8 * 8 * 64) {
      const int pair = t >> 12;
      const int kk = (t >> 9) & 7;
      const int n = (t >> 6) & 7;
      const int l = t & 63;
      const int c = n * 16 + (l & 15);
      const int k0 = kk * 32 + (l >> 4) * 8;
      const float* Wt = pair ? Wt1 : Wt0;
      const float* Ws = pair ? Ws1 : Ws0;
      unsigned v[8];
#pragma unroll
      for (int j = 0; j < 8; ++j) {
        const int k = k0 + j;
        const float f = (k < 128) ? Wt[k * 128 + c] : Ws[(k - 128) * 128 + c];
        v[j] = bf16rne(f);
      }
      uint4 r;
      r.x = v[0] | (v[1] << 16);
      r.y = v[2] | (v[3] << 16);
      r.z = v[4] | (v[5] << 16);
      r.w = v[6] | (v[7] << 16);
      ((uint4*)bp)[t] = r;
    }
  } else {
    // ---- p1: bucket histogram (LDS hist, 1 global atomic per bucket) ----
    for (int k = tid; k < NBUCK; k += 256) lh[k] = 0;
    __syncthreads();
    const int total = 2 * E;
    const int beg = (b - 2080) * CHUNK;
    const int end = min(beg + CHUNK, total);
    for (int i = beg + tid; i < end; i += 256) {
      const int t = (i < E) ? eui_t[i] : (eiu_t[i - E] + kNItem);
      atomicAdd(&lh[bucket_of(t)], 1u);
    }
    __syncthreads();
    for (int k = tid; k < NBUCK; k += 256)
      if (lh[k]) atomicAdd(&gh[k], lh[k]);
  }
}

// ---------------------------------------------------------------------------
// P2: exclusive scan of gh[NBUCK] -> bstart[NBUCK+1]; init gcur = bstart
// ---------------------------------------------------------------------------
__global__ __launch_bounds__(256) void p2_scan_kernel(
    const unsigned* __restrict__ gh, unsigned* __restrict__ bstart,
    unsigned* __restrict__ gcur) {
  __shared__ unsigned ts[256];
  const int tid = threadIdx.x;
  unsigned v[4];
  unsigned tsum = 0;
#pragma unroll
  for (int i = 0; i < 4; ++i) {
    const int idx = tid * 4 + i;
    v[i] = (idx < NBUCK) ? gh[idx] : 0u;
    tsum += v[i];
  }
  ts[tid] = tsum;
  __syncthreads();
  unsigned x = tsum;
  for (int off = 1; off < 256; off <<= 1) {
    const unsigned y = (tid >= off) ? ts[tid - off] : 0u;
    __syncthreads();
    x += y;
    ts[tid] = x;
    __syncthreads();
  }
  unsigned run = x - tsum;
#pragma unroll
  for (int i = 0; i < 4; ++i) {
    const int idx = tid * 4 + i;
    if (idx < NBUCK) { bstart[idx] = run; gcur[idx] = run; }
    run += v[i];
  }
  if (tid == 255) bstart[NBUCK] = run;   // total
}

// ---------------------------------------------------------------------------
// P3: partition edges into bucket-contiguous part[] via LDS staging.
// Entry packed u32: src | (tl << 24). Bucket id recorded in u16 side array
// at scatter time -> flush does a direct lookup (no binary search).
// ---------------------------------------------------------------------------
__global__ __launch_bounds__(256) void p3_partition_kernel(
    const int* __restrict__ eui_s, const int* __restrict__ eui_t,
    const int* __restrict__ eiu_s, const int* __restrict__ eiu_t,
    unsigned* __restrict__ gcur, unsigned* __restrict__ part, int E) {
  __shared__ unsigned lh[NBUCK], lbase[NBUCK], lcur[NBUCK], lpref[NBUCK];
  __shared__ unsigned ts[256];
  __shared__ unsigned lstage[CHUNK];
  __shared__ unsigned short lbuck[CHUNK];
  const int tid = (int)threadIdx.x;
  for (int k = tid; k < NBUCK; k += 256) { lh[k] = 0; lcur[k] = 0; }
  __syncthreads();

  const int total = 2 * E;
  const int beg = (int)blockIdx.x * CHUNK;
  const int end = min(beg + CHUNK, total);
  const int csz = end - beg;

  // pass A: local bucket histogram
  for (int i = beg + tid; i < end; i += 256) {
    const int t = (i < E) ? eui_t[i] : (eiu_t[i - E] + kNItem);
    atomicAdd(&lh[bucket_of(t)], 1u);
  }
  __syncthreads();

  // reserve global ranges + local exclusive scan (lpref)
  for (int k = tid; k < NBUCK; k += 256)
    lbase[k] = lh[k] ? atomicAdd(&gcur[k], lh[k]) : 0u;
  {
    unsigned v[3];
    unsigned tsum = 0;
#pragma unroll
    for (int i = 0; i < 3; ++i) {            // 3*256 = 768 >= NBUCK
      const int idx = tid * 3 + i;
      v[i] = (idx < NBUCK) ? lh[idx] : 0u;
      tsum += v[i];
    }
    ts[tid] = tsum;
    __syncthreads();
    unsigned x = tsum;
    for (int off = 1; off < 256; off <<= 1) {
      const unsigned y = (tid >= off) ? ts[tid - off] : 0u;
      __syncthreads();
      x += y;
      ts[tid] = x;
      __syncthreads();
    }
    unsigned run = x - tsum;
#pragma unroll
    for (int i = 0; i < 3; ++i) {
      const int idx = tid * 3 + i;
      if (idx < NBUCK) lpref[idx] = run;
      run += v[i];
    }
  }
  __syncthreads();

  // pass B: scatter into bucket-sorted LDS staging (+ bucket id)
  for (int i = beg + tid; i < end; i += 256) {
    int s, t;
    if (i < E) { s = eui_s[i]; t = eui_t[i]; }
    else       { s = eiu_s[i - E]; t = eiu_t[i - E] + kNItem; }
    const int k = bucket_of(t);
    const unsigned tl = (t < kNItem) ? (unsigned)(t & 255) : (unsigned)((t - kNItem) & 255);
    const unsigned r = atomicAdd(&lcur[k], 1u);
    const unsigned idx = lpref[k] + r;
    lstage[idx] = (unsigned)s | (tl << 24);
    lbuck[idx] = (unsigned short)k;
  }
  __syncthreads();

  // flush: direct bucket lookup, bucket-contiguous runs to part[]
  for (int j = tid; j < csz; j += 256) {
    const int k = lbuck[j];
    part[lbase[k] + (j - lpref[k])] = lstage[j];
  }
}

// ---------------------------------------------------------------------------
// P4: per-bucket CSR (LDS hist + scan + staged segment -> coalesced writes)
// ---------------------------------------------------------------------------
__global__ __launch_bounds__(256) void p4_csr_kernel(
    const unsigned* __restrict__ part, const unsigned* __restrict__ bstart,
    unsigned* __restrict__ csr, unsigned* __restrict__ offs,
    unsigned* __restrict__ cnt) {
  __shared__ unsigned lcnt[256], lofs[256], lcur[256], ts[256];
  __shared__ unsigned segbuf[SEGCAP];
  const int k = (int)blockIdx.x;
  const int tid = (int)threadIdx.x;
  const unsigned seg0 = bstart[k], seg1 = bstart[k + 1];
  const int tbase = (k < kIB) ? (k << 8) : (kNItem + ((k - kIB) << 8));
  const int tmax = (k < kIB) ? min(256, kNItem - tbase) : min(256, kNTot - tbase);

  lcnt[tid] = 0;
  __syncthreads();
  for (unsigned i = seg0 + tid; i < seg1; i += 256)
    atomicAdd(&lcnt[part[i] >> 24], 1u);
  __syncthreads();

  const unsigned v = lcnt[tid];
  ts[tid] = v;
  __syncthreads();
  unsigned x = v;
  for (int off = 1; off < 256; off <<= 1) {
    const unsigned y = (tid >= off) ? ts[tid - off] : 0u;
    __syncthreads();
    x += y;
    ts[tid] = x;
    __syncthreads();
  }
  lofs[tid] = x - v;
  lcur[tid] = 0;
  if (tid < tmax) { offs[tbase + tid] = seg0 + (x - v); cnt[tbase + tid] = v; }
  __syncthreads();

  for (unsigned i = seg0 + tid; i < seg1; i += 256) {
    const unsigned e = part[i];
    const unsigned tl = e >> 24;
    const unsigned r = atomicAdd(&lcur[tl], 1u);
    const unsigned slot = lofs[tl] + r;
    if (slot < SEGCAP) segbuf[slot] = e & 0x00FFFFFFu;
  }
  __syncthreads();

  const unsigned segsz = min(seg1 - seg0, (unsigned)SEGCAP);
  for (unsigned j = tid; j < segsz; j += 256) csr[seg0 + j] = segbuf[j];
}

// ---------------------------------------------------------------------------
// Aggregate (fp8 gather -> bf16 mean): one wave per combined node.
// 16 lanes/row (8B uint2), 4 edge slots, 16 edges/iter with 4 OUTSTANDING
// loads/lane (measured-best MLP). Decode via v_cvt_pk_f32_fp8; accumulate
// as f32x2 vectors -> v_pk_add_f32 (halves add instructions). Single 4-deep
// guarded 16-edge tail (remainder < 16 after main loop). shfl_xor(16,32).
// ---------------------------------------------------------------------------
__global__ __launch_bounds__(256) void aggregate2_kernel(
    const unsigned char* __restrict__ xf8u, const unsigned char* __restrict__ xf8i,
    const unsigned* __restrict__ csr, const unsigned* __restrict__ offs,
    const unsigned* __restrict__ cnt, unsigned short* __restrict__ meanb) {
  const int lane = (int)(threadIdx.x & 63);
  const int sub = lane >> 4;                           // edge slot 0..3
  const unsigned sl8 = (unsigned)(lane & 15) * 8u;     // byte offset in row
  const int node = (int)((blockIdx.x * 256 + threadIdx.x) >> 6);
  if (node >= kNTot) return;
  const unsigned char* xf = (node < kNItem) ? xf8u : xf8i;
  const unsigned deg = cnt[node];
  const unsigned start = offs[node];
  const unsigned end = start + deg;

  f32x2 a0 = {0.f, 0.f}, a1 = {0.f, 0.f}, a2 = {0.f, 0.f}, a3 = {0.f, 0.f};

  unsigned base = start;
  for (; base + 16 <= end; base += 16) {
    const unsigned s0 = csr[base + sub];
    const unsigned s1 = csr[base + sub + 4];
    const unsigned s2 = csr[base + sub + 8];
    const unsigned s3 = csr[base + sub + 12];
    const uint2 v0 = *(const uint2*)(xf + (size_t)(s0 * 128u + sl8));
    const uint2 v1 = *(const uint2*)(xf + (size_t)(s1 * 128u + sl8));
    const uint2 v2 = *(const uint2*)(xf + (size_t)(s2 * 128u + sl8));
    const uint2 v3 = *(const uint2*)(xf + (size_t)(s3 * 128u + sl8));
#pragma unroll
    for (int h = 0; h < 4; ++h) {
      const uint2 v = (h == 0) ? v0 : (h == 1) ? v1 : (h == 2) ? v2 : v3;
      a0 += __builtin_amdgcn_cvt_pk_f32_fp8((int)v.x, false);
      a1 += __builtin_amdgcn_cvt_pk_f32_fp8((int)v.x, true);
      a2 += __builtin_amdgcn_cvt_pk_f32_fp8((int)v.y, false);
      a3 += __builtin_amdgcn_cvt_pk_f32_fp8((int)v.y, true);
    }
  }
  if (base < end) {                         // single guarded 4-deep tail
    const unsigned i0 = base + sub;
    const unsigned i1 = i0 + 4;
    const unsigned i2 = i0 + 8;
    const unsigned i3 = i0 + 12;
    uint2 v0 = make_uint2(0, 0), v1 = make_uint2(0, 0);
    uint2 v2 = make_uint2(0, 0), v3 = make_uint2(0, 0);
    if (i0 < end) v0 = *(const uint2*)(xf + (size_t)(csr[i0] * 128u + sl8));
    if (i1 < end) v1 = *(const uint2*)(xf + (size_t)(csr[i1] * 128u + sl8));
    if (i2 < end) v2 = *(const uint2*)(xf + (size_t)(csr[i2] * 128u + sl8));
    if (i3 < end) v3 = *(const uint2*)(xf + (size_t)(csr[i3] * 128u + sl8));
#pragma unroll
    for (int h = 0; h < 4; ++h) {
      const uint2 v = (h == 0) ? v0 : (h == 1) ? v1 : (h == 2) ? v2 : v3;
      a0 += __builtin_amdgcn_cvt_pk_f32_fp8((int)v.x, false);
      a1 += __builtin_amdgcn_cvt_pk_f32_fp8((int)v.x, true);
      a2 += __builtin_amdgcn_cvt_pk_f32_fp8((int)v.y, false);
      a3 += __builtin_amdgcn_cvt_pk_f32_fp8((int)v.y, true);
    }
  }

  float acc[8] = {a0.x, a0.y, a1.x, a1.y, a2.x, a2.y, a3.x, a3.y};
#pragma unroll
  for (int j = 0; j < 8; ++j) acc[j] += __shfl_xor(acc[j], 16);
#pragma unroll
  for (int j = 0; j < 8; ++j) acc[j] += __shfl_xor(acc[j], 32);

  if (sub == 0) {
    const float inv = deg ? 1.0f / (float)deg : 0.0f;  // zero rows stay zero
    uint4 r;
    r.x = bf16rne(acc[0] * inv) | (bf16rne(acc[1] * inv) << 16);
    r.y = bf16rne(acc[2] * inv) | (bf16rne(acc[3] * inv) << 16);
    r.z = bf16rne(acc[4] * inv) | (bf16rne(acc[5] * inv) << 16);
    r.w = bf16rne(acc[6] * inv) | (bf16rne(acc[7] * inv) << 16);
    *(uint4*)(meanb + (size_t)node * D_FEAT + sl8) = r;
  }
}

// ---------------------------------------------------------------------------
// Fused MFMA output GEMM over both node types (block-range split), K=256.
// C/D: col = lane&15, row = (lane>>4)*4 + reg   [verified m89 layout]
// ---------------------------------------------------------------------------
__global__ __launch_bounds__(256) void mfma_out2_kernel(
    const unsigned short* __restrict__ xbi, const unsigned short* __restrict__ xbu,
    const unsigned short* __restrict__ meanb,
    const unsigned short* __restrict__ bpack,
    float* __restrict__ out_user, float* __restrict__ out_item, int itemBlocks) {
  const int b = (int)blockIdx.x;
  const unsigned short *xb, *mb, *bp;
  float* out;
  int M, rowb;
  if (b < itemBlocks) {
    M = kNItem; rowb = b * 64;
    xb = xbi; mb = meanb; out = out_item; bp = bpack;
  } else {
    M = kNUser; rowb = (b - itemBlocks) * 64;
    xb = xbu; mb = meanb + (size_t)kNItem * D_FEAT; out = out_user;
    bp = bpack + (size_t)8 * 8 * 64 * 8;
  }
  const int l = (int)(threadIdx.x & 63);
  const int w = (int)(threadIdx.x >> 6);
  rowb += w * 16;
  const int arow = min(rowb + (l & 15), M - 1);
  const int kq8 = (l >> 4) * 8;

  f32x4 acc[8];
#pragma unroll
  for (int n = 0; n < 8; ++n) acc[n] = (f32x4){0.f, 0.f, 0.f, 0.f};

  const unsigned short* ax = xb + (size_t)arow * D_FEAT + kq8;
  const unsigned short* am = mb + (size_t)arow * D_FEAT + kq8;

#pragma unroll
  for (int kk = 0; kk < 8; ++kk) {
    const unsigned short* ap = (kk < 4) ? (ax + kk * 32) : (am + (kk - 4) * 32);
    const bf16x8 a = *(const bf16x8*)ap;
#pragma unroll
    for (int n = 0; n < 8; ++n) {
      const bf16x8 bfr = *(const bf16x8*)(bp + ((size_t)(kk * 8 + n) * 64 + l) * 8);
      acc[n] = __builtin_amdgcn_mfma_f32_16x16x32_bf16(a, bfr, acc[n], 0, 0, 0);
    }
  }

  const int r0 = rowb + (l >> 4) * 4;
  const int col = l & 15;
#pragma unroll
  for (int n = 0; n < 8; ++n) {
#pragma unroll
    for (int r = 0; r < 4; ++r) {
      const int row = r0 + r;
      if (row < M) out[(size_t)row * 128 + n * 16 + col] = acc[n][r];
    }
  }
}

// ---------------------------------------------------------------------------
extern "C" void kernel_launch(void* const* d_in, const int* in_sizes, int n_in,
                              void* d_out, int out_size, void* d_ws, size_t ws_size,
                              hipStream_t stream) {
  const float* x_user  = (const float*)d_in[0];
  const float* x_item  = (const float*)d_in[1];
  const float* W_ui_src = (const float*)d_in[2];
  const float* W_ui_tgt = (const float*)d_in[3];
  const float* W_iu_src = (const float*)d_in[4];
  const float* W_iu_tgt = (const float*)d_in[5];
  const int* edge_ui = (const int*)d_in[6];
  const int* edge_iu = (const int*)d_in[7];
  const int E = in_sizes[6] / 2;   // 1,600,000

  // ws (~78 MB): meanb[150K*128]bf16, xbu[100K*128]bf16, xbi[50K*128]bf16,
  //   bpack[2*256*128]bf16, gh[587], bstart[588], gcur[587],
  //   cnt[150K], offs[150K]
  unsigned short* meanb = (unsigned short*)d_ws;
  unsigned short* xbu   = meanb + (size_t)kNTot * 128;
  unsigned short* xbi   = xbu + (size_t)kNUser * 128;
  unsigned short* bpack = xbi + (size_t)kNItem * 128;
  unsigned* gh     = (unsigned*)(bpack + 2 * 256 * 128);
  unsigned* bstart = gh + NBUCK;
  unsigned* gcur   = bstart + (NBUCK + 1);
  unsigned* cnt    = gcur + NBUCK;
  unsigned* offs   = cnt + kNTot;

  float* out_user = (float*)d_out;                 // return order: user first
  float* out_item = out_user + (size_t)kNUser * 128;

  // d_out scratch (all dead before the GEMM rewrites d_out, same-stream order):
  //   csr[2E] u32 (12.8 MB) @0, part[2E] u32 (12.8 MB), xf8u (12.8 MB),
  //   xf8i (6.4 MB)  -> 44.8 MB of 76.8 MB
  unsigned* csr = (unsigned*)d_out;
  unsigned* part = csr + (size_t)2 * E;
  unsigned char* xf8u = (unsigned char*)(part + (size_t)2 * E);
  unsigned char* xf8i = xf8u + (size_t)kNUser * 128;

  hipMemsetAsync(gh, 0, NBUCK * sizeof(unsigned), stream);

  // fused convert | pack | histogram (2048 + 32 + 512 blocks)
  phase_a_kernel<<<2048 + 32 + NCHUNK, 256, 0, stream>>>(
      x_user, x_item, xbu, xbi, xf8u, xf8i,
      W_ui_tgt, W_ui_src, W_iu_tgt, W_iu_src, bpack,
      edge_ui + E, edge_iu + E, gh,
      kNUser * 128 / 8, kNTot * 128 / 8, E);

  p2_scan_kernel<<<1, 256, 0, stream>>>(gh, bstart, gcur);
  p3_partition_kernel<<<NCHUNK, 256, 0, stream>>>(
      edge_ui, edge_ui + E, edge_iu, edge_iu + E, gcur, part, E);
  p4_csr_kernel<<<NBUCK, 256, 0, stream>>>(part, bstart, csr, offs, cnt);

  aggregate2_kernel<<<(kNTot * 64 + 255) / 256, 256, 0, stream>>>(
      xf8u, xf8i, csr, offs, cnt, meanb);

  const int itemBlocks = (kNItem + 63) / 64;       // 782
  const int userBlocks = (kNUser + 63) / 64;       // 1563
  mfma_out2_kernel<<<itemBlocks + userBlocks, 256, 0, stream>>>(
      xbi, xbu, meanb, bpack, out_user, out_item, itemBlocks);
}